// Round 2
// baseline (1223.461 us; speedup 1.0000x reference)
//
#include <hip/hip_runtime.h>
#include <hip/hip_bf16.h>

// SwiGLU MoE (T=4096, H=2048, I=2048, E=8, top-2) for gfx950.
// Pipeline: convert hs->bf16 | router(top2 via sigmoid(l0-l1)) | prefix |
//           grouped fc1+swiglu (bf16 MFMA) -> y bf16 | grouped fc2 + gated atomic combine.

#define T_TOK 4096
#define HD    2048
#define ID    2048
#define I2    4096
#define NE    8

typedef __attribute__((ext_vector_type(8))) short  bf16x8;
typedef __attribute__((ext_vector_type(4))) float  f32x4;

// ---- workspace layout (bytes); total need ~52.3 MB ----
#define WS_CNT   0
#define WS_OFF   64
#define WS_TOK   1024
#define WS_GATE  (WS_TOK + NE*T_TOK*4)            // 132096
#define WS_HS    270336                            // bf16 hidden states, 16 MiB
#define WS_Y     (WS_HS + T_TOK*HD*2 + 2048)       // y buffer, bf16
#define Y_ROWS   (2*T_TOK + NE*128)                // 9216 rows max (128-aligned per-expert)

__device__ __forceinline__ unsigned short f2b(float f){
    __hip_bfloat16 h = __float2bfloat16(f);
    unsigned short u; __builtin_memcpy(&u, &h, 2); return u;
}

__device__ __forceinline__ void gload16(const void* g, void* l){
    __builtin_amdgcn_global_load_lds(
        (const __attribute__((address_space(1))) unsigned int*)g,
        (__attribute__((address_space(3))) unsigned int*)l, 16, 0, 0);
}

// ---- hs f32 -> bf16 ----
__global__ __launch_bounds__(256) void k_convert(
    const float* __restrict__ src, unsigned short* __restrict__ dst, int n4)
{
    int i = blockIdx.x*256 + threadIdx.x;
    const int stride = gridDim.x*256;
    for (; i < n4; i += stride) {
        float4 v = ((const float4*)src)[i];
        ushort4 o;
        o.x=f2b(v.x); o.y=f2b(v.y); o.z=f2b(v.z); o.w=f2b(v.w);
        ((ushort4*)dst)[i] = o;
    }
}

// ---- router: one wave per token ----
__global__ __launch_bounds__(64) void k_router(
    const float* __restrict__ hs, const float* __restrict__ rw,
    int* __restrict__ cnt, int* __restrict__ tok, float* __restrict__ gate)
{
    const int t = blockIdx.x, lane = threadIdx.x;
    const float4* h4 = (const float4*)(hs + (size_t)t*HD);
    const float4* r4 = (const float4*)rw;

    float acc[NE] = {};
    for (int j = 0; j < HD/4; j += 64) {
        float4 hv = h4[lane + j];
#pragma unroll
        for (int e2 = 0; e2 < NE; ++e2) {
            float4 wv = r4[e2*(HD/4) + lane + j];
            acc[e2] += hv.x*wv.x + hv.y*wv.y + hv.z*wv.z + hv.w*wv.w;
        }
    }
#pragma unroll
    for (int e2 = 0; e2 < NE; ++e2)
        for (int off = 32; off; off >>= 1)
            acc[e2] += __shfl_xor(acc[e2], off);

    if (lane == 0) {
        int i0 = 0; float v0 = acc[0];
        for (int e2 = 1; e2 < NE; ++e2) if (acc[e2] > v0) { v0 = acc[e2]; i0 = e2; }
        int i1 = -1; float v1 = -3.0e38f;
        for (int e2 = 0; e2 < NE; ++e2) if (e2 != i0 && acc[e2] > v1) { v1 = acc[e2]; i1 = e2; }
        // renormalized top-2 softmax == sigmoid of logit gap
        float g0 = 1.0f / (1.0f + __expf(v1 - v0));
        float g1 = 1.0f - g0;
        int p0 = atomicAdd(&cnt[i0], 1);
        tok[i0*T_TOK + p0] = t;  gate[i0*T_TOK + p0] = g0;
        int p1 = atomicAdd(&cnt[i1], 1);
        tok[i1*T_TOK + p1] = t;  gate[i1*T_TOK + p1] = g1;
    }
}

// ---- 128-aligned exclusive prefix of expert counts ----
__global__ void k_prefix(const int* __restrict__ cnt, int* __restrict__ offs){
    if (threadIdx.x == 0) {
        int o = 0;
        for (int e2 = 0; e2 < NE; ++e2) { offs[e2] = o; o += (cnt[e2] + 127) & ~127; }
    }
}

// ---- fc1 + interleaved SwiGLU (grouped GEMM, 128 tokens x 64 I-cols per block) ----
// B rows de-interleaved: LDS rows 0..63 = weight rows 2(i0+j) (glu), 64..127 = 2(i0+j)+1 (lin).
// 4 waves stacked along M => pair partner of acc[m][n] is acc[m][n+4] in the SAME lane.
__global__ __launch_bounds__(256) void k_fc1(
    const unsigned short* __restrict__ hsb,
    const float* __restrict__ w1, const float* __restrict__ b1,
    const int* __restrict__ cnt, const int* __restrict__ offs,
    const int* __restrict__ tok, unsigned short* __restrict__ yb)
{
    const int e = blockIdx.z;
    const int count = cnt[e];
    const int m0 = blockIdx.y * 128;
    if (m0 >= count) return;
    const int i0 = blockIdx.x * 64;

    const int tid = threadIdx.x, lane = tid & 63, wv = tid >> 6;

    __shared__ unsigned short A_lds[128*64];
    __shared__ unsigned short B_lds[128*64];

    // A: gathered token rows; 4x 1KB global_load_lds issues per wave (8 rows each)
    const unsigned short* aptr[4];
#pragma unroll
    for (int i = 0; i < 4; ++i) {
        int row = (wv*4 + i)*8 + (lane>>3);
        int s   = m0 + row;
        int tk  = (s < count) ? tok[e*T_TOK + s] : 0;
        aptr[i] = hsb + (size_t)tk*HD + (lane&7)*8;
    }

    const int brow = tid >> 1, half = tid & 1;
    const int wrow = (brow < 64) ? 2*(i0 + brow) : 2*(i0 + brow - 64) + 1;
    const float* bsrc = w1 + ((size_t)e*I2 + wrow)*HD + half*32;
    unsigned short* bdst = &B_lds[brow*64 + half*32];

    f32x4 acc[2][8] = {};

    for (int k0 = 0; k0 < HD; k0 += 64) {
#pragma unroll
        for (int i = 0; i < 4; ++i)
            gload16(aptr[i] + k0, &A_lds[(wv*4 + i)*512]);

        float4 f[8];
#pragma unroll
        for (int i = 0; i < 8; ++i)
            f[i] = *((const float4*)(bsrc + k0) + i);
        union { unsigned short u[32]; bf16x8 v[4]; } c;
#pragma unroll
        for (int i = 0; i < 8; ++i) {
            c.u[4*i+0]=f2b(f[i].x); c.u[4*i+1]=f2b(f[i].y);
            c.u[4*i+2]=f2b(f[i].z); c.u[4*i+3]=f2b(f[i].w);
        }
#pragma unroll
        for (int i = 0; i < 4; ++i)
            *((bf16x8*)bdst + i) = c.v[i];

        __syncthreads();

#pragma unroll
        for (int kk = 0; kk < 2; ++kk) {
            const int lk = kk*32 + (lane>>4)*8;
            bf16x8 a[2], b[8];
#pragma unroll
            for (int m = 0; m < 2; ++m)
                a[m] = *(const bf16x8*)&A_lds[(wv*32 + m*16 + (lane&15))*64 + lk];
#pragma unroll
            for (int n = 0; n < 8; ++n)
                b[n] = *(const bf16x8*)&B_lds[(n*16 + (lane&15))*64 + lk];
#pragma unroll
            for (int m = 0; m < 2; ++m)
#pragma unroll
                for (int n = 0; n < 8; ++n)
                    acc[m][n] = __builtin_amdgcn_mfma_f32_16x16x32_bf16(a[m], b[n], acc[m][n], 0, 0, 0);
        }
        __syncthreads();
    }

    const int col = lane & 15, rg = lane >> 4;
    const float2* b1p = (const float2*)(b1 + (size_t)e*I2);
    const int yoff = offs[e];

    float2 bb[4];
#pragma unroll
    for (int n = 0; n < 4; ++n) bb[n] = b1p[i0 + n*16 + col];

#pragma unroll
    for (int m = 0; m < 2; ++m) {
#pragma unroll
        for (int j = 0; j < 4; ++j) {
            int s = m0 + wv*32 + m*16 + rg*4 + j;
            if (s >= count) continue;
            size_t ybase = (size_t)(yoff + s)*ID + i0;
#pragma unroll
            for (int n = 0; n < 4; ++n) {
                float xg = acc[m][n][j]   + bb[n].x;
                float xl = acc[m][n+4][j] + bb[n].y;
                xg = fminf(xg, 7.0f);
                xl = fminf(fmaxf(xl, -7.0f), 7.0f);
                float sg = 1.0f / (1.0f + __expf(-1.702f * xg));
                yb[ybase + n*16 + col] = f2b(xg * sg * (xl + 1.0f));
            }
        }
    }
}

// ---- fc2 + gated atomic combine (128 rows x 128 H-cols per block) ----
__global__ __launch_bounds__(256) void k_fc2(
    const unsigned short* __restrict__ yb,
    const float* __restrict__ w2, const float* __restrict__ b2,
    const int* __restrict__ cnt, const int* __restrict__ offs,
    const int* __restrict__ tok, const float* __restrict__ gate,
    float* __restrict__ out)
{
    const int e = blockIdx.z;
    const int count = cnt[e];
    const int m0 = blockIdx.y * 128;
    if (m0 >= count) return;
    const int h0 = blockIdx.x * 128;

    const int tid = threadIdx.x, lane = tid & 63, wv = tid >> 6;

    __shared__ unsigned short A_lds[128*64];
    __shared__ unsigned short B_lds[128*64];

    const int yoff = offs[e];
    const unsigned short* aptr[4];
#pragma unroll
    for (int i = 0; i < 4; ++i) {
        int row = (wv*4 + i)*8 + (lane>>3);
        aptr[i] = yb + (size_t)(yoff + m0 + row)*ID + (lane&7)*8;  // padded rows in-capacity
    }

    const int brow = tid >> 1, half = tid & 1;
    const float* bsrc = w2 + ((size_t)e*HD + h0 + brow)*ID + half*32;
    unsigned short* bdst = &B_lds[brow*64 + half*32];

    f32x4 acc[2][8] = {};

    for (int k0 = 0; k0 < ID; k0 += 64) {
#pragma unroll
        for (int i = 0; i < 4; ++i)
            gload16(aptr[i] + k0, &A_lds[(wv*4 + i)*512]);

        float4 f[8];
#pragma unroll
        for (int i = 0; i < 8; ++i)
            f[i] = *((const float4*)(bsrc + k0) + i);
        union { unsigned short u[32]; bf16x8 v[4]; } c;
#pragma unroll
        for (int i = 0; i < 8; ++i) {
            c.u[4*i+0]=f2b(f[i].x); c.u[4*i+1]=f2b(f[i].y);
            c.u[4*i+2]=f2b(f[i].z); c.u[4*i+3]=f2b(f[i].w);
        }
#pragma unroll
        for (int i = 0; i < 4; ++i)
            *((bf16x8*)bdst + i) = c.v[i];

        __syncthreads();

#pragma unroll
        for (int kk = 0; kk < 2; ++kk) {
            const int lk = kk*32 + (lane>>4)*8;
            bf16x8 a[2], b[8];
#pragma unroll
            for (int m = 0; m < 2; ++m)
                a[m] = *(const bf16x8*)&A_lds[(wv*32 + m*16 + (lane&15))*64 + lk];
#pragma unroll
            for (int n = 0; n < 8; ++n)
                b[n] = *(const bf16x8*)&B_lds[(n*16 + (lane&15))*64 + lk];
#pragma unroll
            for (int m = 0; m < 2; ++m)
#pragma unroll
                for (int n = 0; n < 8; ++n)
                    acc[m][n] = __builtin_amdgcn_mfma_f32_16x16x32_bf16(a[m], b[n], acc[m][n], 0, 0, 0);
        }
        __syncthreads();
    }

    const int col = lane & 15, rg = lane >> 4;
    float bcol[8];
#pragma unroll
    for (int n = 0; n < 8; ++n) bcol[n] = b2[(size_t)e*HD + h0 + n*16 + col];

#pragma unroll
    for (int m = 0; m < 2; ++m) {
#pragma unroll
        for (int j = 0; j < 4; ++j) {
            int s = m0 + wv*32 + m*16 + rg*4 + j;
            if (s >= count) continue;
            int   tk = tok[e*T_TOK + s];
            float g  = gate[e*T_TOK + s];
            float* orow = out + (size_t)tk*HD + h0;
#pragma unroll
            for (int n = 0; n < 8; ++n)
                atomicAdd(orow + n*16 + col, (acc[m][n][j] + bcol[n]) * g);
        }
    }
}

extern "C" void kernel_launch(void* const* d_in, const int* in_sizes, int n_in,
                              void* d_out, int out_size, void* d_ws, size_t ws_size,
                              hipStream_t stream)
{
    const float* hs = (const float*)d_in[0];
    const float* rw = (const float*)d_in[1];
    const float* w1 = (const float*)d_in[2];
    const float* b1 = (const float*)d_in[3];
    const float* w2 = (const float*)d_in[4];
    const float* b2 = (const float*)d_in[5];
    float* out = (float*)d_out;

    char* ws = (char*)d_ws;
    int*   cnt  = (int*)(ws + WS_CNT);
    int*   offs = (int*)(ws + WS_OFF);
    int*   tok  = (int*)(ws + WS_TOK);
    float* gate = (float*)(ws + WS_GATE);
    unsigned short* hsb = (unsigned short*)(ws + WS_HS);
    unsigned short* yb  = (unsigned short*)(ws + WS_Y);

    hipMemsetAsync(ws, 0, 128, stream);                                // counts + offsets
    hipMemsetAsync(d_out, 0, (size_t)out_size*sizeof(float), stream);  // atomic accumulate target

    k_convert<<<2048, 256, 0, stream>>>(hs, hsb, T_TOK*HD/4);
    k_router <<<T_TOK, 64, 0, stream>>>(hs, rw, cnt, tok, gate);
    k_prefix <<<1, 64, 0, stream>>>(cnt, offs);
    k_fc1    <<<dim3(I2/128, T_TOK/128, NE), 256, 0, stream>>>(hsb, w1, b1, cnt, offs, tok, yb);
    k_fc2    <<<dim3(HD/128, T_TOK/128, NE), 256, 0, stream>>>(yb, w2, b2, cnt, offs, tok, gate, out);
}